// Round 9
// baseline (103.370 us; speedup 1.0000x reference)
//
#include <hip/hip_runtime.h>
#include <math.h>

// Sampler: temperature 0.8, top-k (k=50 input), top-p 0.9, inverse-CDF
// multinomial. B=128 rows, V=128000, fp32 logits -> int32 ids.
//
// R9: two kernels, full-device scan parallelism (R6-R8's one-block-per-row
// used only 128 of 256 CUs and plateaued at ~1.5 TB/s logical).
//  K1 scan: B x 16 blocks, 256 thr, slice = 2048 float4. Each thread loads
//    its 8 NAMED float4 back-to-back (true 8-deep MLP, no loop carry),
//    max-of-4 pre-filter, pushes candidates (y >= 11.2, x >= 14; ~20/slice)
//    via LDS atomics, then plain-stores its PRIVATE 64-entry global segment
//    + count. Zero global atomics (R2 lesson), zero fences (R5 lesson).
//  K2 select: B blocks x 1024 thr. Wave-0 shuffle prefix over 16 counts,
//    one-wave-per-segment gather (single global-latency round), two-tier
//    filter (x >= 16 when count >= k -> M ~ 88; provably superset of
//    top-k + kth ties), rank sort (x desc, idx asc == jnp.argsort(-x)),
//    then the R7 block-parallel tail (shuffle reductions/scans + ballot
//    counts; fp32 margins >> rounding). absmax-0 lineage R1-R8.
//  Fallback (any segment overflow / total < k): exact kth via binary search
//    on float key bits + rescan. Never fires on this data.

#define SLICES   16
#define SEGCAP   64
#define SLICE_F4 2048
#define MSORT    1024

__device__ __forceinline__ unsigned fkey(float y) {
    unsigned b = __float_as_uint(y);
    return (b & 0x80000000u) ? ~b : (b | 0x80000000u);  // y asc -> key asc
}

// block-wide sum over 1024 threads; wpart = shared float[16]; ends synced
__device__ __forceinline__ float block_sum(float v, int tid, float* wpart) {
#pragma unroll
    for (int off = 32; off > 0; off >>= 1) v += __shfl_down(v, off, 64);
    if ((tid & 63) == 0) wpart[tid >> 6] = v;
    __syncthreads();
    if (tid < 64) {
        float s = (tid < 16) ? wpart[tid] : 0.0f;
#pragma unroll
        for (int off = 8; off > 0; off >>= 1) s += __shfl_down(s, off, 64);
        if (tid == 0) wpart[0] = s;
    }
    __syncthreads();
    float s = wpart[0];
    __syncthreads();
    return s;
}

// in-place block inclusive scan of arr[0..n), n <= 1024; ends synced
__device__ __forceinline__ void incl_scan(float* arr, int n, int tid, float* wpart) {
    float v = (tid < n) ? arr[tid] : 0.0f;
#pragma unroll
    for (int off = 1; off < 64; off <<= 1) {
        float o = __shfl_up(v, off, 64);
        if ((tid & 63) >= off) v += o;
    }
    if ((tid & 63) == 63) wpart[tid >> 6] = v;
    __syncthreads();
    if (tid < 64) {
        float w = (tid < 16) ? wpart[tid] : 0.0f;
#pragma unroll
        for (int off = 1; off < 16; off <<= 1) {
            float o = __shfl_up(w, off, 64);
            if (tid >= off) w += o;
        }
        if (tid < 16) wpart[tid] = w;
    }
    __syncthreads();
    const int wv = tid >> 6;
    const float base = (wv > 0) ? wpart[wv - 1] : 0.0f;
    if (tid < n) arr[tid] = v + base;
    __syncthreads();
}

// ---------------- Kernel 1: full-device streaming candidate scan ------------
__global__ __launch_bounds__(256)
void scan_kernel(const float* __restrict__ logits, int V,
                 int* __restrict__ scnt,
                 float* __restrict__ cy, int* __restrict__ ci)
{
    constexpr float YTH = 11.2f;   // x = 14.0
    __shared__ float lcy[SEGCAP];
    __shared__ int   lci[SEGCAP];
    __shared__ int   lcnt;

    const int tid = threadIdx.x;
    const int row = blockIdx.x / SLICES;
    const int sl  = blockIdx.x % SLICES;
    if (tid == 0) lcnt = 0;
    __syncthreads();

    const float* rowp = logits + (size_t)row * (size_t)V;
    const float4* rp4 = (const float4*)rowp;
    const int n4   = V >> 2;
    const int s0   = sl * SLICE_F4;
    const int send = (sl == SLICES - 1) ? n4 : min(s0 + SLICE_F4, n4);

#define PUSH4(vv, i4)                                                            \
    {                                                                            \
        float _m = fmaxf(fmaxf((vv).x, (vv).y), fmaxf((vv).z, (vv).w));          \
        if (_m >= YTH) {                                                         \
            if ((vv).x >= YTH) { int _p = atomicAdd(&lcnt, 1);                   \
                if (_p < SEGCAP) { lcy[_p] = (vv).x; lci[_p] = (i4) * 4;     } } \
            if ((vv).y >= YTH) { int _p = atomicAdd(&lcnt, 1);                   \
                if (_p < SEGCAP) { lcy[_p] = (vv).y; lci[_p] = (i4) * 4 + 1; } } \
            if ((vv).z >= YTH) { int _p = atomicAdd(&lcnt, 1);                   \
                if (_p < SEGCAP) { lcy[_p] = (vv).z; lci[_p] = (i4) * 4 + 2; } } \
            if ((vv).w >= YTH) { int _p = atomicAdd(&lcnt, 1);                   \
                if (_p < SEGCAP) { lcy[_p] = (vv).w; lci[_p] = (i4) * 4 + 3; } } \
        }                                                                        \
    }

    if (send - s0 == SLICE_F4) {
        // full slice: exactly 8 strided float4 per thread, straight-line loads
        const int i0 = s0 + tid;
        float4 a0 = rp4[i0];
        float4 a1 = rp4[i0 + 256];
        float4 a2 = rp4[i0 + 512];
        float4 a3 = rp4[i0 + 768];
        float4 a4 = rp4[i0 + 1024];
        float4 a5 = rp4[i0 + 1280];
        float4 a6 = rp4[i0 + 1536];
        float4 a7 = rp4[i0 + 1792];
        PUSH4(a0, i0);
        PUSH4(a1, i0 + 256);
        PUSH4(a2, i0 + 512);
        PUSH4(a3, i0 + 768);
        PUSH4(a4, i0 + 1024);
        PUSH4(a5, i0 + 1280);
        PUSH4(a6, i0 + 1536);
        PUSH4(a7, i0 + 1792);
    } else {
        for (int i = s0 + tid; i < send; i += 256) {
            float4 a = rp4[i];
            PUSH4(a, i);
        }
    }
    if (sl == SLICES - 1) {   // scalar tail if V % 4 != 0
        for (int i = (n4 << 2) + tid; i < V; i += 256) {
            float y = rowp[i];
            if (y >= YTH) {
                int p = atomicAdd(&lcnt, 1);
                if (p < SEGCAP) { lcy[p] = y; lci[p] = i; }
            }
        }
    }
#undef PUSH4
    __syncthreads();

    const int cnt = lcnt;
    float* cyr = cy + ((size_t)row * SLICES + sl) * SEGCAP;
    int*   cir = ci + ((size_t)row * SLICES + sl) * SEGCAP;
    for (int p = tid; p < min(cnt, SEGCAP); p += 256) {
        cyr[p] = lcy[p];
        cir[p] = lci[p];
    }
    if (tid == 0) scnt[row * SLICES + sl] = cnt;  // cnt > SEGCAP => overflow
}

// ---------------- Kernel 2: per-row selection + sampling --------------------
__global__ __launch_bounds__(1024)
void select_kernel(const float* __restrict__ logits,
                   const float* __restrict__ uvec,
                   const int* __restrict__ topk_p,
                   const int* __restrict__ scnt,
                   const float* __restrict__ cy, const int* __restrict__ ci,
                   int* __restrict__ out, int V)
{
    constexpr float TEMP = 0.8f;
    constexpr float TOPP = 0.9f;
    constexpr float XTH2 = 16.0f;   // two-tier threshold in x-space

    __shared__ float gv[MSORT];     // gathered x   -> later sorted values
    __shared__ int   gi[MSORT];     // gathered idx -> later sorted indices
    __shared__ float cv[MSORT];     // compacted x  -> later se = exp(x-max)
    __shared__ int   cidx[MSORT];   // compacted idx-> later vocab-order idx
    __shared__ float sq[MSORT];     // top-p cdf -> probs / sampling cdf
    __shared__ float wpart[16];
    __shared__ float kth_sh;
    __shared__ int   segoff[SLICES + 1];
    __shared__ int   bad_sh, hi_cnt, cpos, scount, cnt_sh, M_sh, tie_cnt, L_cnt, ans_sh;

    const int tid  = threadIdx.x;
    const int lane = tid & 63;
    const int row  = blockIdx.x;
    const int nth  = blockDim.x;    // 1024
    const int k_in = *topk_p;

    const float* rowp = logits + (size_t)row * (size_t)V;

    if (tid == 0) { hi_cnt = 0; cpos = 0; scount = 0;
                    tie_cnt = 0; L_cnt = 0; ans_sh = V; }
    // wave 0: counts + shuffle prefix (one global round)
    if (tid < 64) {
        int c = (tid < SLICES) ? scnt[row * SLICES + tid] : 0;
        int bad = (tid < SLICES) && (c > SEGCAP);
        int acc = min(c, SEGCAP);
#pragma unroll
        for (int off = 1; off < SLICES; off <<= 1) {
            int o = __shfl_up(acc, off, 64);
            if (tid >= off) acc += o;
        }
        if (tid < SLICES) segoff[tid + 1] = acc;
        if (tid == 0) segoff[0] = 0;
        unsigned long long bm = __ballot(bad);
        if (tid == 0) bad_sh = (bm != 0ULL);
    }
    __syncthreads();

    const int M_all = segoff[SLICES];
    int M;
    if (!bad_sh && M_all >= k_in && M_all <= MSORT) {
        // gather: wave s reads segment s (c <= 64 -> one lane per entry)
        {
            const int s = tid >> 6;         // 0..15
            const int off = segoff[s];
            const int c   = segoff[s + 1] - off;
            if (lane < c) {
                const size_t base = ((size_t)row * SLICES + s) * SEGCAP + lane;
                gv[off + lane] = cy[base] / TEMP;
                gi[off + lane] = ci[base];
            }
        }
        __syncthreads();
        // two-tier count
        {
            bool pred = (tid < M_all) && (gv[tid] >= XTH2);
            unsigned long long bm = __ballot(pred);
            if (lane == 0 && bm) atomicAdd(&hi_cnt, (int)__popcll(bm));
        }
        __syncthreads();
        // compact, wave-aggregated
        const float thr = (hi_cnt >= k_in) ? XTH2 : -1e38f;
        {
            bool pred = (tid < M_all) && (gv[tid] >= thr);
            unsigned long long bm = __ballot(pred);
            if (bm) {
                int fl = (int)__ffsll(bm) - 1;
                int bs = 0;
                if (pred && lane == fl) bs = atomicAdd(&cpos, (int)__popcll(bm));
                bs = __shfl(bs, fl, 64);
                if (pred) {
                    int p = bs + (int)__popcll(bm & ((1ULL << lane) - 1ULL));
                    cv[p] = gv[tid]; cidx[p] = gi[tid];
                }
            }
        }
        __syncthreads();
        M = cpos;
    } else {
        // exact fallback: kth value via binary search on float key bits
        unsigned lo = 0;
        for (int bit = 31; bit >= 0; --bit) {
            unsigned t = lo | (1u << bit);
            int local = 0;
            for (int i = tid; i < V; i += nth) local += (fkey(rowp[i]) >= t);
            if (tid == 0) cnt_sh = 0;
            __syncthreads();
            atomicAdd(&cnt_sh, local);
            __syncthreads();
            if (cnt_sh >= k_in) lo = t;
            __syncthreads();
        }
        for (int i = tid; i < V; i += nth) {
            float y = rowp[i];
            if (fkey(y) >= lo) {
                int p = atomicAdd(&scount, 1);
                if (p < MSORT) { cv[p] = y / TEMP; cidx[p] = i; }
            }
        }
        __syncthreads();
        M = min(scount, MSORT);
    }
    if (tid == 0) M_sh = M;
    __syncthreads();
    M = M_sh;

    // pad to multiple of 4 with sentinels (branch-free unrolled inner loop)
    const int Mpad = (M + 3) & ~3;
    for (int t = M + tid; t < Mpad; t += nth) { cv[t] = -1e38f; cidx[t] = 0x7fffffff; }
    __syncthreads();

    // rank sort: x desc, tie idx asc (== argsort(-x)); 1 elem/thread
    if (tid < M) {
        const float v = cv[tid]; const int ix = cidx[tid];
        int r = 0;
        for (int j = 0; j < Mpad; j += 4) {
            float v0 = cv[j],     v1 = cv[j + 1];
            float v2 = cv[j + 2], v3 = cv[j + 3];
            int   i0 = cidx[j],     i1 = cidx[j + 1];
            int   i2 = cidx[j + 2], i3 = cidx[j + 3];
            r += (v0 > v || (v0 == v && i0 < ix));
            r += (v1 > v || (v1 == v && i1 < ix));
            r += (v2 > v || (v2 == v && i2 < ix));
            r += (v3 > v || (v3 == v && i3 < ix));
        }
        gv[r] = v; gi[r] = ix;      // gv/gi now hold the sorted list
    }
    __syncthreads();

    // ---- parallel tail (R7) ----
    const int kk = (M > 0) ? min(max(k_in, 1), M) : 0;
    const float mm = (M > 0) ? gv[0] : 0.0f;
    if (tid < M) cv[tid] = expf(gv[tid] - mm);            // cv = se
    if (tid == 0 && M > 0) kth_sh = gv[kk - 1];
    __syncthreads();

    // ties with the kth value (sorted => contiguous): Kp = kk + #equal
    {
        bool f = (M > 0) && (tid >= kk) && (tid < M) && (gv[tid] == kth_sh);
        unsigned long long bm = __ballot(f);
        if (lane == 0 && bm) atomicAdd(&tie_cnt, (int)__popcll(bm));
    }
    __syncthreads();
    const int Kp = kk + tie_cnt;

    // sum1 = sum(se[0..Kp))
    const float sum1 = block_sum((tid < Kp) ? cv[tid] : 0.0f, tid, wpart);

    // top-p: Q = inclusive cdf of se/sum1; L = 1 + #{i in [1,Kp): Q[i-1]<=p}
    if (tid < Kp) sq[tid] = cv[tid] / sum1;
    incl_scan(sq, Kp, tid, wpart);
    {
        bool f = (tid >= 1) && (tid < Kp) && (sq[tid - 1] <= TOPP);
        unsigned long long bm = __ballot(f);
        if (lane == 0 && bm) atomicAdd(&L_cnt, (int)__popcll(bm));
    }
    __syncthreads();
    const int L = (M > 0) ? (1 + L_cnt) : 0;

    // sum2 = sum(se[0..L))
    const float sum2 = block_sum((tid < L) ? cv[tid] : 0.0f, tid, wpart);

    // reorder kept entries by vocab index: sq[r] = prob, cidx[r] = idx
    if (tid < L) {
        const int ix = gi[tid];
        int r = 0;
        for (int j = 0; j < L; ++j) r += (gi[j] < ix);
        sq[r] = cv[tid] / sum2;
        cidx[r] = ix;
    }
    __syncthreads();

    // sampling cdf + unique crossing: first i with C[i] > u
    incl_scan(sq, L, tid, wpart);
    {
        const float uu = uvec[row];
        bool f = (tid < L) && (sq[tid] > uu) && (tid == 0 || sq[tid - 1] <= uu);
        if (f) ans_sh = cidx[tid];   // unique by monotonicity
    }
    __syncthreads();
    if (tid == 0) out[row] = ans_sh;   // default V if no crossing (u >= total)
}

extern "C" void kernel_launch(void* const* d_in, const int* in_sizes, int n_in,
                              void* d_out, int out_size, void* d_ws, size_t ws_size,
                              hipStream_t stream) {
    const float* logits = (const float*)d_in[0];
    const float* u      = (const float*)d_in[1];
    const int*   topk   = (const int*)d_in[2];
    int*         out    = (int*)d_out;

    const int B = out_size;              // 128 rows
    const int V = in_sizes[0] / B;       // 128000

    // ws layout: scnt[B*SLICES] | cy[B*SLICES*SEGCAP f32] | ci[same i32]
    const size_t n_scnt = (size_t)B * SLICES;
    const size_t n_seg  = (size_t)B * SLICES * SEGCAP;
    int*   scnt = (int*)d_ws;
    float* cy   = (float*)((char*)d_ws + n_scnt * 4);
    int*   ci   = (int*)((char*)d_ws + n_scnt * 4 + n_seg * 4);

    scan_kernel<<<B * SLICES, 256, 0, stream>>>(logits, V, scnt, cy, ci);
    select_kernel<<<B, 1024, 0, stream>>>(logits, u, topk, scnt, cy, ci, out, V);
}